// Round 1
// baseline (165.943 us; speedup 1.0000x reference)
//
#include <hip/hip_runtime.h>

// Problem constants (B,C,H,W)=(2,256,56,56), Cr=64, K=7, G=16, stride=1
#define HW    3136          // 56*56
#define C_IN  256
#define CR    64
#define KKG   784           // 49*16
#define NB    2             // batch
#define BN_EPS 1e-5f

// Scratch in device globals (fully rewritten every call; no cross-call state dependence)
__device__ float g_T[NB * CR * HW];      // conv1 output (pre-BN)
__device__ float g_scale[CR];
__device__ float g_shift[CR];

// ---------------- K1: T = w1 @ x + b1 ----------------
// grid (13, 4, 2), block 256. Each block: 16 output channels x 256 pixels.
__global__ __launch_bounds__(256) void k1_conv1(const float* __restrict__ x,
                                                const float* __restrict__ w1,
                                                const float* __restrict__ b1) {
  int l  = blockIdx.x * 256 + threadIdx.x;
  int o0 = blockIdx.y * 16;
  int b  = blockIdx.z;
  if (l >= HW) return;

  float acc[16];
#pragma unroll
  for (int i = 0; i < 16; ++i) acc[i] = b1[o0 + i];

  const float* xb = x + (size_t)(b * C_IN) * HW + l;
  const float* w  = w1 + (size_t)o0 * C_IN;
#pragma unroll 4
  for (int c = 0; c < C_IN; ++c) {
    float xv = xb[(size_t)c * HW];            // coalesced across lanes
#pragma unroll
    for (int i = 0; i < 16; ++i)
      acc[i] += w[i * C_IN + c] * xv;         // wave-uniform -> s_load
  }
  float* Tb = g_T + (size_t)(b * CR + o0) * HW + l;
#pragma unroll
  for (int i = 0; i < 16; ++i) Tb[(size_t)i * HW] = acc[i];
}

// ---------------- K2: per-channel batch stats -> scale/shift ----------------
// grid (64), block 256. mean/var over (B,H,W) = 6272 elements per channel.
__global__ __launch_bounds__(256) void k2_stats(const float* __restrict__ gamma,
                                                const float* __restrict__ beta) {
  int o = blockIdx.x;
  float s = 0.f, s2 = 0.f;
  for (int b = 0; b < NB; ++b) {
    const float* Tb = g_T + (size_t)(b * CR + o) * HW;
    for (int l = threadIdx.x; l < HW; l += 256) {
      float v = Tb[l];
      s += v; s2 += v * v;
    }
  }
  // 64-lane wave reduce, then cross-wave via LDS
#pragma unroll
  for (int off = 32; off > 0; off >>= 1) {
    s  += __shfl_down(s, off);
    s2 += __shfl_down(s2, off);
  }
  __shared__ float sd[8];
  int lane = threadIdx.x & 63, wid = threadIdx.x >> 6;
  if (lane == 0) { sd[wid] = s; sd[4 + wid] = s2; }
  __syncthreads();
  if (threadIdx.x == 0) {
    float S  = sd[0] + sd[1] + sd[2] + sd[3];
    float S2 = sd[4] + sd[5] + sd[6] + sd[7];
    const float invN = 1.0f / (NB * HW);
    float mean = S * invN;
    float var  = S2 * invN - mean * mean;    // population var (ddof=0) matches jnp.var
    float inv  = rsqrtf(var + BN_EPS);
    float sc   = gamma[o] * inv;
    g_scale[o] = sc;
    g_shift[o] = beta[o] - mean * sc;
  }
}

// ---------------- K3: kout = w2 @ relu(BN(T)) + b2 ----------------
// grid (13, 49, 2), block 256. Each block: 16 output channels x 256 pixels.
__global__ __launch_bounds__(256) void k3_conv2(const float* __restrict__ w2,
                                                const float* __restrict__ b2,
                                                float* __restrict__ kout) {
  int l  = blockIdx.x * 256 + threadIdx.x;
  int o0 = blockIdx.y * 16;
  int b  = blockIdx.z;
  if (l >= HW) return;

  float acc[16];
#pragma unroll
  for (int i = 0; i < 16; ++i) acc[i] = b2[o0 + i];

  const float* Tb = g_T + (size_t)(b * CR) * HW + l;
  const float* w  = w2 + (size_t)o0 * CR;
#pragma unroll 4
  for (int c = 0; c < CR; ++c) {
    float tv = Tb[(size_t)c * HW];
    tv = fmaxf(tv * g_scale[c] + g_shift[c], 0.0f);   // fused BN + ReLU
#pragma unroll
    for (int i = 0; i < 16; ++i)
      acc[i] += w[i * CR + c] * tv;                   // wave-uniform -> s_load
  }
  float* kb = kout + (size_t)(b * KKG + o0) * HW + l;
#pragma unroll
  for (int i = 0; i < 16; ++i) kb[(size_t)i * HW] = acc[i];
}

// ---------------- K4: involution gather-reduce ----------------
// out flat f = cg*50176 + base  (per batch).  base = s*3136 + u, u -> pixel.
// kernel value: kflat[b][kk*50176 + base]  (cg-invariant)
// x value:      x[b][16*cg + d][yy*56+xx], d=(16*kk+s)/49, kk'=(16*kk+s)%49,
//               ki=kk'/7, kj=kk'%7, yy=u/56+ki-3, xx=u%56+kj-3 (0 if OOB)
// grid (196, 2), block 256; one thread per base, 16 cg accumulators.
__global__ __launch_bounds__(256) void k4_invol(const float* __restrict__ x,
                                                const float* __restrict__ kout,
                                                float* __restrict__ out) {
  int base = blockIdx.x * 256 + threadIdx.x;   // [0, 50176)
  int b    = blockIdx.y;

  int s = base / HW;                 // [0,16)
  int u = base - s * HW;             // [0,3136)
  int yrow = u / 56;
  int yy0 = yrow - 3;
  int xx0 = (u - yrow * 56) - 3;

  const float* kb = kout + (size_t)b * (KKG * HW) + base;
  const float* xb = x + (size_t)b * (C_IN * HW);

  float acc[16];
#pragma unroll
  for (int i = 0; i < 16; ++i) acc[i] = 0.0f;

#pragma unroll 7
  for (int kk = 0; kk < 49; ++kk) {
    int t16 = 16 * kk + s;
    int d   = t16 / 49;              // cg-invariant channel offset
    int kkp = t16 - d * 49;
    int ki  = kkp / 7;
    int kj  = kkp - ki * 7;
    int yy = yy0 + ki, xx = xx0 + kj;
    float kv = kb[(size_t)kk * 50176];
    int off;
    if ((unsigned)yy < 56u && (unsigned)xx < 56u) {
      off = yy * 56 + xx;
    } else {
      off = 0;                       // safe address; kv=0 kills the term
      kv = 0.0f;
    }
    const float* xp = xb + (size_t)d * HW + off;
#pragma unroll
    for (int cg = 0; cg < 16; ++cg)
      acc[cg] += kv * xp[(size_t)cg * 50176];   // c' = 16*cg + d
  }

  float* ob = out + (size_t)b * (C_IN * HW) + base;
#pragma unroll
  for (int cg = 0; cg < 16; ++cg) ob[(size_t)cg * 50176] = acc[cg];
}

extern "C" void kernel_launch(void* const* d_in, const int* in_sizes, int n_in,
                              void* d_out, int out_size, void* d_ws, size_t ws_size,
                              hipStream_t stream) {
  const float* x     = (const float*)d_in[0];
  const float* w1    = (const float*)d_in[1];
  const float* b1    = (const float*)d_in[2];
  const float* gamma = (const float*)d_in[3];
  const float* beta  = (const float*)d_in[4];
  const float* w2    = (const float*)d_in[5];
  const float* b2    = (const float*)d_in[6];

  float* out  = (float*)d_out;                       // (B,256,56,56)
  float* kout = out + (size_t)NB * C_IN * HW;        // (B,784,56,56) raw == (B,49,56,56,16)

  k1_conv1<<<dim3(13, 4, NB), 256, 0, stream>>>(x, w1, b1);
  k2_stats<<<dim3(CR), 256, 0, stream>>>(gamma, beta);
  k3_conv2<<<dim3(13, 49, NB), 256, 0, stream>>>(w2, b2, kout);
  k4_invol<<<dim3(196, NB), 256, 0, stream>>>(x, kout, out);
}

// Round 2
// 144.232 us; speedup vs baseline: 1.1505x; 1.1505x over previous
//
#include <hip/hip_runtime.h>

// Problem constants (B,C,H,W)=(2,256,56,56), Cr=64, K=7, G=16, stride=1
#define HW     3136          // 56*56
#define C_IN   256
#define CR     64
#define KKG    784           // 49*16
#define NB     2             // batch
#define NPIX   6272          // NB*HW
#define BN_EPS 1e-5f

// Device-global scratch (fully rewritten every call)
__device__ float g_P[4 * CR * NPIX];     // K-split partials of conv1: [kc][o][p]
__device__ float g_T[CR * NPIX];         // conv1 output (pre-BN): [o][p], p = b*HW+u
__device__ float g_stat[2 * CR];         // per-channel sum / sumsq
__device__ float g_scale[CR];
__device__ float g_shift[CR];

// ---------------- K1a: conv1 partials, K-split by 4 ----------------
// grid (25, 16, 4), block 256. Each thread: 1 pixel x 4 o-channels x 64 input chans.
__global__ __launch_bounds__(256) void k1a_conv1(const float* __restrict__ x,
                                                 const float* __restrict__ w1) {
  // zero the stats accumulator for this call (K1b runs after full K1a completion)
  if (blockIdx.x == 0 && blockIdx.y == 0 && blockIdx.z == 0 && threadIdx.x < 2 * CR)
    g_stat[threadIdx.x] = 0.0f;

  int p = blockIdx.x * 256 + threadIdx.x;   // [0, 6272)
  if (p >= NPIX) return;
  int o0 = blockIdx.y * 4;
  int kc = blockIdx.z;                      // input-channel chunk, 64 chans each
  int b  = p / HW;
  int u  = p - b * HW;

  const float* xb = x + ((size_t)(b * C_IN + kc * 64)) * HW + u;
  const float* w  = w1 + kc * 64;           // w1[o*256 + kc*64 + c]

  float a0 = 0.f, a1 = 0.f, a2 = 0.f, a3 = 0.f;
#pragma unroll 8
  for (int c = 0; c < 64; ++c) {
    float xv = xb[(size_t)c * HW];          // coalesced across lanes
    a0 += w[(o0 + 0) * C_IN + c] * xv;      // wave-uniform -> s_load
    a1 += w[(o0 + 1) * C_IN + c] * xv;
    a2 += w[(o0 + 2) * C_IN + c] * xv;
    a3 += w[(o0 + 3) * C_IN + c] * xv;
  }
  float* pp = g_P + ((size_t)kc * CR + o0) * NPIX + p;
  pp[0 * NPIX] = a0; pp[1 * NPIX] = a1; pp[2 * NPIX] = a2; pp[3 * NPIX] = a3;
}

// ---------------- K1b: reduce partials + b1 -> T, fused batch stats ----------------
// grid (25, 64), block 256. One thread per T element; block-reduce sum/sumsq -> atomics.
__global__ __launch_bounds__(256) void k1b_reduce(const float* __restrict__ b1) {
  int p = blockIdx.x * 256 + threadIdx.x;
  int o = blockIdx.y;
  float v = 0.0f;
  bool valid = (p < NPIX);
  if (valid) {
    v = b1[o]
      + g_P[((size_t)0 * CR + o) * NPIX + p]
      + g_P[((size_t)1 * CR + o) * NPIX + p]
      + g_P[((size_t)2 * CR + o) * NPIX + p]
      + g_P[((size_t)3 * CR + o) * NPIX + p];
    g_T[(size_t)o * NPIX + p] = v;
  }
  float s = valid ? v : 0.0f;
  float s2 = s * v * (valid ? 1.0f : 0.0f);
  s2 = valid ? v * v : 0.0f;
#pragma unroll
  for (int off = 32; off > 0; off >>= 1) {
    s  += __shfl_down(s, off);
    s2 += __shfl_down(s2, off);
  }
  __shared__ float sd[8];
  int lane = threadIdx.x & 63, wid = threadIdx.x >> 6;
  if (lane == 0) { sd[wid] = s; sd[4 + wid] = s2; }
  __syncthreads();
  if (threadIdx.x == 0) {
    atomicAdd(&g_stat[o],      sd[0] + sd[1] + sd[2] + sd[3]);
    atomicAdd(&g_stat[CR + o], sd[4] + sd[5] + sd[6] + sd[7]);
  }
}

// ---------------- K2: scale/shift from stats (1 block, 64 threads) ----------------
__global__ void k2_scaleshift(const float* __restrict__ gamma,
                              const float* __restrict__ beta) {
  int o = threadIdx.x;
  float S = g_stat[o], S2 = g_stat[CR + o];
  const float invN = 1.0f / (float)NPIX;
  float mean = S * invN;
  float var  = S2 * invN - mean * mean;     // population var matches jnp.var
  float inv  = rsqrtf(var + BN_EPS);
  float sc   = gamma[o] * inv;
  g_scale[o] = sc;
  g_shift[o] = beta[o] - mean * sc;
}

// ---------------- K3: kout = w2 @ relu(BN(T)) + b2 ----------------
// grid (13, 49, 2), block 256. Each block: 16 output channels x 256 pixels.
__global__ __launch_bounds__(256) void k3_conv2(const float* __restrict__ w2,
                                                const float* __restrict__ b2,
                                                float* __restrict__ kout) {
  int l  = blockIdx.x * 256 + threadIdx.x;
  int o0 = blockIdx.y * 16;
  int b  = blockIdx.z;
  if (l >= HW) return;

  float acc[16];
#pragma unroll
  for (int i = 0; i < 16; ++i) acc[i] = b2[o0 + i];

  const float* Tb = g_T + (size_t)b * HW + l;     // g_T[c*NPIX + b*HW + l]
  const float* w  = w2 + (size_t)o0 * CR;
#pragma unroll 4
  for (int c = 0; c < CR; ++c) {
    float tv = Tb[(size_t)c * NPIX];
    tv = fmaxf(tv * g_scale[c] + g_shift[c], 0.0f);   // fused BN + ReLU
#pragma unroll
    for (int i = 0; i < 16; ++i)
      acc[i] += w[i * CR + c] * tv;                   // wave-uniform -> s_load
  }
  float* kb = kout + (size_t)(b * KKG + o0) * HW + l;
#pragma unroll
  for (int i = 0; i < 16; ++i) kb[(size_t)i * HW] = acc[i];
}

// ---------------- K4: involution gather-reduce, cg-split by 2 ----------------
// out flat f = cg*50176 + base (per batch). base = s*3136 + u.
// kernel value: kflat[b][kk*50176 + base] (cg-invariant)
// x value: x[b][16*cg + d][yy*56+xx], d=(16*kk+s)/49, kk'=(16*kk+s)%49,
//          ki=kk'/7, kj=kk'%7, yy=u/56+ki-3, xx=u%56+kj-3 (0 if OOB)
// grid (196, 2, 2), block 256; one thread per base, 8 cg accumulators per block-half.
__global__ __launch_bounds__(256) void k4_invol(const float* __restrict__ x,
                                                const float* __restrict__ kout,
                                                float* __restrict__ out) {
  int base = blockIdx.x * 256 + threadIdx.x;   // [0, 50176)
  int b    = blockIdx.y;
  int cg0  = blockIdx.z * 8;

  int s = base / HW;                 // [0,16)
  int u = base - s * HW;             // [0,3136)
  int yrow = u / 56;
  int yy0 = yrow - 3;
  int xx0 = (u - yrow * 56) - 3;

  const float* kb = kout + (size_t)b * (KKG * HW) + base;
  const float* xb = x + (size_t)b * (C_IN * HW) + (size_t)cg0 * 50176;

  float acc[8];
#pragma unroll
  for (int i = 0; i < 8; ++i) acc[i] = 0.0f;

#pragma unroll 7
  for (int kk = 0; kk < 49; ++kk) {
    int t16 = 16 * kk + s;
    int d   = t16 / 49;              // cg-invariant channel offset
    int kkp = t16 - d * 49;
    int ki  = kkp / 7;
    int kj  = kkp - ki * 7;
    int yy = yy0 + ki, xx = xx0 + kj;
    float kv = kb[(size_t)kk * 50176];
    int off;
    if ((unsigned)yy < 56u && (unsigned)xx < 56u) {
      off = yy * 56 + xx;
    } else {
      off = 0;                       // safe address; kv=0 kills the term
      kv = 0.0f;
    }
    const float* xp = xb + (size_t)d * HW + off;
#pragma unroll
    for (int cg = 0; cg < 8; ++cg)
      acc[cg] += kv * xp[(size_t)cg * 50176];   // c' = 16*(cg0+cg) + d
  }

  float* ob = out + (size_t)b * (C_IN * HW) + (size_t)cg0 * 50176 + base;
#pragma unroll
  for (int cg = 0; cg < 8; ++cg) ob[(size_t)cg * 50176] = acc[cg];
}

extern "C" void kernel_launch(void* const* d_in, const int* in_sizes, int n_in,
                              void* d_out, int out_size, void* d_ws, size_t ws_size,
                              hipStream_t stream) {
  const float* x     = (const float*)d_in[0];
  const float* w1    = (const float*)d_in[1];
  const float* b1    = (const float*)d_in[2];
  const float* gamma = (const float*)d_in[3];
  const float* beta  = (const float*)d_in[4];
  const float* w2    = (const float*)d_in[5];
  const float* b2    = (const float*)d_in[6];

  float* out  = (float*)d_out;                       // (B,256,56,56)
  float* kout = out + (size_t)NB * C_IN * HW;        // (B,784,56,56) raw == (B,49,56,56,16)

  k1a_conv1<<<dim3(25, 16, 4), 256, 0, stream>>>(x, w1);
  k1b_reduce<<<dim3(25, CR), 256, 0, stream>>>(b1);
  k2_scaleshift<<<dim3(1), 64, 0, stream>>>(gamma, beta);
  k3_conv2<<<dim3(13, 49, NB), 256, 0, stream>>>(w2, b2, kout);
  k4_invol<<<dim3(196, NB, 2), 256, 0, stream>>>(x, kout, out);
}

// Round 3
// 141.384 us; speedup vs baseline: 1.1737x; 1.0201x over previous
//
#include <hip/hip_runtime.h>

// Problem constants (B,C,H,W)=(2,256,56,56), Cr=64, K=7, G=16, stride=1
#define HW     3136          // 56*56
#define C_IN   256
#define CR     64
#define KKG    784           // 49*16
#define NB     2             // batch
#define NPIX   6272          // NB*HW
#define NT25   25            // p-tiles of 256 over NPIX
#define BN_EPS 1e-5f

// Device-global scratch (fully rewritten every call; no cross-call state)
__device__ float g_P[4 * CR * NPIX];       // K-split conv1 partials [kc][o][p]
__device__ float g_T[CR * NPIX];           // conv1 output (pre-BN) [o][p]
__device__ float g_bs[2 * CR * NT25];      // per-block partial sum/sumsq [2][o][px]
__device__ float g_ss[2 * CR];             // scale[0..63], shift[64..127]
__device__ float g_xg[16 * NPIX * 16];     // x transposed: [d][p][cg] = x[b][16cg+d][hw]

// ---------------- K1a: conv1 partials, K-split by 4 ----------------
// grid (25, 16, 4), block 256. Each thread: 1 pixel x 4 o-channels x 64 input chans.
__global__ __launch_bounds__(256) void k1a_conv1(const float* __restrict__ x,
                                                 const float* __restrict__ w1) {
  int p = blockIdx.x * 256 + threadIdx.x;   // [0, 6272)
  if (p >= NPIX) return;
  int o0 = blockIdx.y * 4;
  int kc = blockIdx.z;                      // input-channel chunk, 64 chans each
  int b  = p / HW;
  int u  = p - b * HW;

  const float* xb = x + ((size_t)(b * C_IN + kc * 64)) * HW + u;
  const float* w  = w1 + kc * 64;           // w1[o*256 + kc*64 + c]

  float a0 = 0.f, a1 = 0.f, a2 = 0.f, a3 = 0.f;
#pragma unroll 8
  for (int c = 0; c < 64; ++c) {
    float xv = xb[(size_t)c * HW];          // coalesced across lanes
    a0 += w[(o0 + 0) * C_IN + c] * xv;      // wave-uniform -> s_load
    a1 += w[(o0 + 1) * C_IN + c] * xv;
    a2 += w[(o0 + 2) * C_IN + c] * xv;
    a3 += w[(o0 + 3) * C_IN + c] * xv;
  }
  float* pp = g_P + ((size_t)kc * CR + o0) * NPIX + p;
  pp[0 * NPIX] = a0; pp[1 * NPIX] = a1; pp[2 * NPIX] = a2; pp[3 * NPIX] = a3;
}

// ---------------- K1b: reduce partials + b1 -> T, per-block stats ----------------
// grid (25, 64), block 256. Deterministic: block (px,o) writes g_bs[o][px].
__global__ __launch_bounds__(256) void k1b_reduce(const float* __restrict__ b1) {
  int p = blockIdx.x * 256 + threadIdx.x;
  int o = blockIdx.y;
  bool valid = (p < NPIX);
  float v = 0.0f;
  if (valid) {
    v = b1[o]
      + g_P[((size_t)0 * CR + o) * NPIX + p]
      + g_P[((size_t)1 * CR + o) * NPIX + p]
      + g_P[((size_t)2 * CR + o) * NPIX + p]
      + g_P[((size_t)3 * CR + o) * NPIX + p];
    g_T[(size_t)o * NPIX + p] = v;
  }
  float s  = valid ? v : 0.0f;
  float s2 = valid ? v * v : 0.0f;
#pragma unroll
  for (int off = 32; off > 0; off >>= 1) {
    s  += __shfl_down(s, off);
    s2 += __shfl_down(s2, off);
  }
  __shared__ float sd[8];
  int lane = threadIdx.x & 63, wid = threadIdx.x >> 6;
  if (lane == 0) { sd[wid] = s; sd[4 + wid] = s2; }
  __syncthreads();
  if (threadIdx.x == 0) {
    g_bs[o * NT25 + blockIdx.x]             = sd[0] + sd[1] + sd[2] + sd[3];
    g_bs[CR * NT25 + o * NT25 + blockIdx.x] = sd[4] + sd[5] + sd[6] + sd[7];
  }
}

// ---------------- K0t: transpose x -> x_g[d][p][cg]; block(0,0) finalizes BN ----------------
// grid (16, 25), block 256. Reads coalesced per cg-row, writes 64B/lane contiguous.
__global__ __launch_bounds__(256) void k0t_transpose(const float* __restrict__ x,
                                                     const float* __restrict__ gamma,
                                                     const float* __restrict__ beta) {
  int d = blockIdx.x;
  int p = blockIdx.y * 256 + threadIdx.x;
  if (p < NPIX) {
    int b  = (p >= HW) ? 1 : 0;
    int hw = p - b * HW;
    const float* xp = x + ((size_t)(b * C_IN + d)) * HW + hw;
    float r[16];
#pragma unroll
    for (int cg = 0; cg < 16; ++cg)
      r[cg] = xp[(size_t)cg * (16 * HW)];
    float4* dst = (float4*)(g_xg + (((size_t)d * NPIX + p) << 4));
    dst[0] = make_float4(r[0], r[1], r[2], r[3]);
    dst[1] = make_float4(r[4], r[5], r[6], r[7]);
    dst[2] = make_float4(r[8], r[9], r[10], r[11]);
    dst[3] = make_float4(r[12], r[13], r[14], r[15]);
  }
  // finalize BN scale/shift once (needs g_bs from k1b, complete by stream order)
  if (blockIdx.x == 0 && blockIdx.y == 0 && threadIdx.x < CR) {
    int o = threadIdx.x;
    float S = 0.f, S2 = 0.f;
#pragma unroll
    for (int px = 0; px < NT25; ++px) {
      S  += g_bs[o * NT25 + px];
      S2 += g_bs[CR * NT25 + o * NT25 + px];
    }
    const float invN = 1.0f / (float)NPIX;
    float mean = S * invN;
    float var  = S2 * invN - mean * mean;   // population var matches jnp.var
    float inv  = rsqrtf(var + BN_EPS);
    float sc   = gamma[o] * inv;
    g_ss[o]      = sc;
    g_ss[CR + o] = beta[o] - mean * sc;
  }
}

// ---------------- K3: kout = w2 @ relu(BN(T)) + b2 ----------------
// grid (13, 49, 2), block 256. Each block: 16 output channels x 256 pixels.
__global__ __launch_bounds__(256) void k3_conv2(const float* __restrict__ w2,
                                                const float* __restrict__ b2,
                                                float* __restrict__ kout) {
  __shared__ float ssc[CR], ssh[CR];
  if (threadIdx.x < 2 * CR) {
    float v = g_ss[threadIdx.x];
    if (threadIdx.x < CR) ssc[threadIdx.x] = v; else ssh[threadIdx.x - CR] = v;
  }
  __syncthreads();

  int l  = blockIdx.x * 256 + threadIdx.x;
  if (l >= HW) return;
  int o0 = blockIdx.y * 16;
  int b  = blockIdx.z;

  float acc[16];
#pragma unroll
  for (int i = 0; i < 16; ++i) acc[i] = b2[o0 + i];

  const float* Tb = g_T + (size_t)b * HW + l;     // g_T[c*NPIX + b*HW + l]
  const float* w  = w2 + (size_t)o0 * CR;
#pragma unroll 4
  for (int c = 0; c < CR; ++c) {
    float tv = Tb[(size_t)c * NPIX];
    tv = fmaxf(tv * ssc[c] + ssh[c], 0.0f);       // fused BN + ReLU (LDS broadcast)
#pragma unroll
    for (int i = 0; i < 16; ++i)
      acc[i] += w[i * CR + c] * tv;               // wave-uniform -> s_load
  }
  float* kb = kout + (size_t)(b * KKG + o0) * HW + l;
#pragma unroll
  for (int i = 0; i < 16; ++i) kb[(size_t)i * HW] = acc[i];
}

// ---------------- K4: involution gather-reduce, cg-split by 2, float4 x-loads ----------------
// out flat f = cg*50176 + base (per batch). base = s*3136 + u.
// kernel value: kflat[b][kk*50176 + base] (cg-invariant)
// x value via x_g: x_g[d][b*HW + pix][cg], d=(16kk+s)/49, kk'=(16kk+s)%49,
//   ki=kk'/7, kj=kk'%7, pix=(u/56+ki-3)*56 + (u%56+kj-3), 0 if OOB.
// grid (196, 2, 2), block 256; one thread per base, 8 cg accumulators per z-half.
__global__ __launch_bounds__(256) void k4_invol(const float* __restrict__ kout,
                                                float* __restrict__ out) {
  int base = blockIdx.x * 256 + threadIdx.x;   // [0, 50176)
  int b    = blockIdx.y;
  int cg0  = blockIdx.z * 8;

  int s = base / HW;                 // [0,16)
  int u = base - s * HW;             // [0,3136)
  int yrow = u / 56;
  int yy0 = yrow - 3;
  int xx0 = (u - yrow * 56) - 3;

  const float* kb = kout + (size_t)b * (KKG * HW) + base;

  float acc[8];
#pragma unroll
  for (int i = 0; i < 8; ++i) acc[i] = 0.0f;

#pragma unroll 7
  for (int kk = 0; kk < 49; ++kk) {
    int t16 = 16 * kk + s;
    int d   = t16 / 49;              // cg-invariant channel offset
    int kkp = t16 - d * 49;
    int ki  = kkp / 7;
    int kj  = kkp - ki * 7;
    int yy = yy0 + ki, xx = xx0 + kj;
    float kv = kb[(size_t)kk * 50176];
    int off;
    if ((unsigned)yy < 56u && (unsigned)xx < 56u) {
      off = yy * 56 + xx;
    } else {
      off = 0;                       // safe address; kv=0 kills the term
      kv = 0.0f;
    }
    const float* xp = g_xg + ((((size_t)d * NPIX + b * HW + off) << 4) + cg0);
    float4 xa = *(const float4*)xp;
    float4 xb4 = *(const float4*)(xp + 4);
    acc[0] += kv * xa.x;  acc[1] += kv * xa.y;
    acc[2] += kv * xa.z;  acc[3] += kv * xa.w;
    acc[4] += kv * xb4.x; acc[5] += kv * xb4.y;
    acc[6] += kv * xb4.z; acc[7] += kv * xb4.w;
  }

  float* ob = out + (size_t)b * (C_IN * HW) + (size_t)cg0 * 50176 + base;
#pragma unroll
  for (int cg = 0; cg < 8; ++cg) ob[(size_t)cg * 50176] = acc[cg];
}

extern "C" void kernel_launch(void* const* d_in, const int* in_sizes, int n_in,
                              void* d_out, int out_size, void* d_ws, size_t ws_size,
                              hipStream_t stream) {
  const float* x     = (const float*)d_in[0];
  const float* w1    = (const float*)d_in[1];
  const float* b1    = (const float*)d_in[2];
  const float* gamma = (const float*)d_in[3];
  const float* beta  = (const float*)d_in[4];
  const float* w2    = (const float*)d_in[5];
  const float* b2    = (const float*)d_in[6];

  float* out  = (float*)d_out;                       // (B,256,56,56)
  float* kout = out + (size_t)NB * C_IN * HW;        // (B,784,56,56) raw == (B,49,56,56,16)

  k1a_conv1<<<dim3(25, 16, 4), 256, 0, stream>>>(x, w1);
  k1b_reduce<<<dim3(25, CR), 256, 0, stream>>>(b1);
  k0t_transpose<<<dim3(16, NT25), 256, 0, stream>>>(x, gamma, beta);
  k3_conv2<<<dim3(13, 49, NB), 256, 0, stream>>>(w2, b2, kout);
  k4_invol<<<dim3(196, NB, 2), 256, 0, stream>>>(kout, out);
}

// Round 4
// 139.142 us; speedup vs baseline: 1.1926x; 1.0161x over previous
//
#include <hip/hip_runtime.h>

// Problem constants (B,C,H,W)=(2,256,56,56), Cr=64, K=7, G=16, stride=1
#define HW     3136          // 56*56
#define C_IN   256
#define CR     64
#define KKG    784           // 49*16
#define NB     2             // batch
#define NPIX   6272          // NB*HW
#define NT25   25            // p-tiles of 256 over NPIX
#define BN_EPS 1e-5f

// Device-global scratch (fully rewritten every call; no cross-call state)
__device__ float g_P[4 * CR * NPIX];       // K-split conv1 partials [kc][o][p]
__device__ float g_T[CR * NPIX];           // conv1 output (pre-BN) [o][p]
__device__ float g_bs[2 * CR * NT25];      // per-block partial sum/sumsq [2][o][px]
__device__ float g_xg[16 * NPIX * 16];     // x transposed: [d][p][cg] = x[b][16cg+d][hw]

// ---------------- K1a: conv1 partials, K-split by 4 ----------------
// grid (25, 16, 4), block 256. Each thread: 1 pixel x 4 o-channels x 64 input chans.
__global__ __launch_bounds__(256) void k1a_conv1(const float* __restrict__ x,
                                                 const float* __restrict__ w1) {
  int p = blockIdx.x * 256 + threadIdx.x;   // [0, 6272)
  if (p >= NPIX) return;
  int o0 = blockIdx.y * 4;
  int kc = blockIdx.z;                      // input-channel chunk, 64 chans each
  int b  = p / HW;
  int u  = p - b * HW;

  const float* xb = x + ((size_t)(b * C_IN + kc * 64)) * HW + u;
  const float* w  = w1 + kc * 64;           // w1[o*256 + kc*64 + c]

  float a0 = 0.f, a1 = 0.f, a2 = 0.f, a3 = 0.f;
#pragma unroll 8
  for (int c = 0; c < 64; ++c) {
    float xv = xb[(size_t)c * HW];          // coalesced across lanes
    a0 += w[(o0 + 0) * C_IN + c] * xv;      // wave-uniform -> s_load
    a1 += w[(o0 + 1) * C_IN + c] * xv;
    a2 += w[(o0 + 2) * C_IN + c] * xv;
    a3 += w[(o0 + 3) * C_IN + c] * xv;
  }
  float* pp = g_P + ((size_t)kc * CR + o0) * NPIX + p;
  pp[0 * NPIX] = a0; pp[1 * NPIX] = a1; pp[2 * NPIX] = a2; pp[3 * NPIX] = a3;
}

// ---------------- kRT: fused (reduce partials -> T + partial stats) | (transpose x) ----
// grid (25, 80), block 256.
//   y in [0,64): reduce for o=y at p-tile x; write g_T and g_bs[o][px].
//   y in [64,80): transpose slice d=y-64 at p-tile x into g_xg.
__global__ __launch_bounds__(256) void kRT(const float* __restrict__ x,
                                           const float* __restrict__ b1) {
  int p = blockIdx.x * 256 + threadIdx.x;
  if (blockIdx.y < 64) {
    int o = blockIdx.y;
    bool valid = (p < NPIX);
    float v = 0.0f;
    if (valid) {
      v = b1[o]
        + g_P[((size_t)0 * CR + o) * NPIX + p]
        + g_P[((size_t)1 * CR + o) * NPIX + p]
        + g_P[((size_t)2 * CR + o) * NPIX + p]
        + g_P[((size_t)3 * CR + o) * NPIX + p];
      g_T[(size_t)o * NPIX + p] = v;
    }
    float s  = valid ? v : 0.0f;
    float s2 = valid ? v * v : 0.0f;
#pragma unroll
    for (int off = 32; off > 0; off >>= 1) {
      s  += __shfl_down(s, off);
      s2 += __shfl_down(s2, off);
    }
    __shared__ float sd[8];
    int lane = threadIdx.x & 63, wid = threadIdx.x >> 6;
    if (lane == 0) { sd[wid] = s; sd[4 + wid] = s2; }
    __syncthreads();
    if (threadIdx.x == 0) {
      g_bs[o * NT25 + blockIdx.x]             = sd[0] + sd[1] + sd[2] + sd[3];
      g_bs[CR * NT25 + o * NT25 + blockIdx.x] = sd[4] + sd[5] + sd[6] + sd[7];
    }
  } else {
    int d = blockIdx.y - 64;
    if (p >= NPIX) return;
    int b  = (p >= HW) ? 1 : 0;
    int hw = p - b * HW;
    const float* xp = x + ((size_t)(b * C_IN + d)) * HW + hw;
    float r[16];
#pragma unroll
    for (int cg = 0; cg < 16; ++cg)
      r[cg] = xp[(size_t)cg * (16 * HW)];
    float4* dst = (float4*)(g_xg + (((size_t)d * NPIX + p) << 4));
    dst[0] = make_float4(r[0], r[1], r[2], r[3]);
    dst[1] = make_float4(r[4], r[5], r[6], r[7]);
    dst[2] = make_float4(r[8], r[9], r[10], r[11]);
    dst[3] = make_float4(r[12], r[13], r[14], r[15]);
  }
}

// ---------------- K3: kout = w2 @ relu(BN(T)) + b2, BN finalized per-block ----------------
// grid (13, 49, 2), block 256. Each block: 16 output channels x 256 pixels.
__global__ __launch_bounds__(256) void k3_conv2(const float* __restrict__ gamma,
                                                const float* __restrict__ beta,
                                                const float* __restrict__ w2,
                                                const float* __restrict__ b2,
                                                float* __restrict__ kout) {
  __shared__ float ssc[CR], ssh[CR];
  if (threadIdx.x < CR) {
    int o = threadIdx.x;
    float S = 0.f, S2 = 0.f;
#pragma unroll
    for (int px = 0; px < NT25; ++px) {
      S  += g_bs[o * NT25 + px];
      S2 += g_bs[CR * NT25 + o * NT25 + px];
    }
    const float invN = 1.0f / (float)NPIX;
    float mean = S * invN;
    float var  = S2 * invN - mean * mean;   // population var matches jnp.var
    float inv  = rsqrtf(var + BN_EPS);
    float sc   = gamma[o] * inv;
    ssc[o] = sc;
    ssh[o] = beta[o] - mean * sc;
  }
  __syncthreads();

  int l  = blockIdx.x * 256 + threadIdx.x;
  if (l >= HW) return;
  int o0 = blockIdx.y * 16;
  int b  = blockIdx.z;

  float acc[16];
#pragma unroll
  for (int i = 0; i < 16; ++i) acc[i] = b2[o0 + i];

  const float* Tb = g_T + (size_t)b * HW + l;     // g_T[c*NPIX + b*HW + l]
  const float* w  = w2 + (size_t)o0 * CR;
#pragma unroll 4
  for (int c = 0; c < CR; ++c) {
    float tv = Tb[(size_t)c * NPIX];
    tv = fmaxf(tv * ssc[c] + ssh[c], 0.0f);       // fused BN + ReLU (LDS broadcast)
#pragma unroll
    for (int i = 0; i < 16; ++i)
      acc[i] += w[i * CR + c] * tv;               // wave-uniform -> s_load
  }
  float* kb = kout + (size_t)(b * KKG + o0) * HW + l;
#pragma unroll
  for (int i = 0; i < 16; ++i) kb[(size_t)i * HW] = acc[i];
}

// ---------------- K4: involution, s-per-block (uniform index math), float4 x-loads ----
// out[b][16cg+s][u] = sum_kk kout[b][16kk+s][u] * x_g[d][b*HW+pix][cg]
//   d=(16kk+s)/49, kk'=(16kk+s)%49, ki=kk'/7, kj=kk'%7,
//   pix=(u/56+ki-3)*56 + (u%56+kj-3), term dropped if OOB.
// grid (13, 16, 4), block 256: x=u-tile, y=s (uniform!), z=b*2+cg-half.
__global__ __launch_bounds__(256) void k4_invol(const float* __restrict__ kout,
                                                float* __restrict__ out) {
  int u = blockIdx.x * 256 + threadIdx.x;     // [0, 3136)
  if (u >= HW) return;
  int s   = blockIdx.y;                        // wave-uniform
  int bz  = blockIdx.z;
  int b   = bz >> 1;
  int cg0 = (bz & 1) * 8;

  int yrow = u / 56;
  int col  = u - yrow * 56;

  const float* kb = kout + (size_t)b * (KKG * HW) + (size_t)s * HW + u;
  const float* xg = g_xg + cg0;
  const size_t bHW16 = (size_t)(b * HW) << 4;

  float acc[8];
#pragma unroll
  for (int i = 0; i < 8; ++i) acc[i] = 0.0f;

#pragma unroll 7
  for (int kk = 0; kk < 49; ++kk) {
    int t16 = 16 * kk + s;          // scalar
    int d   = t16 / 49;             // scalar (SALU magic-mul)
    int kkp = t16 - d * 49;         // scalar
    int ki  = kkp / 7;              // scalar
    int kj  = kkp - ki * 7;         // scalar
    int yy = yrow + ki - 3, xx = col + kj - 3;
    float kv = kb[(size_t)kk * (16 * HW)];
    int off;
    if ((unsigned)yy < 56u && (unsigned)xx < 56u) {
      off = yy * 56 + xx;
    } else {
      off = 0;                      // safe address; kv=0 kills the term
      kv = 0.0f;
    }
    const float* xp = xg + (((size_t)d * NPIX + off) << 4) + bHW16;
    float4 xa  = *(const float4*)xp;
    float4 xb4 = *(const float4*)(xp + 4);
    acc[0] += kv * xa.x;  acc[1] += kv * xa.y;
    acc[2] += kv * xa.z;  acc[3] += kv * xa.w;
    acc[4] += kv * xb4.x; acc[5] += kv * xb4.y;
    acc[6] += kv * xb4.z; acc[7] += kv * xb4.w;
  }

  // out channel c = 16*(cg0+cg) + s
  float* ob = out + (size_t)b * (C_IN * HW) + ((size_t)(16 * cg0 + s)) * HW + u;
#pragma unroll
  for (int cg = 0; cg < 8; ++cg) ob[(size_t)cg * (16 * HW)] = acc[cg];
}

extern "C" void kernel_launch(void* const* d_in, const int* in_sizes, int n_in,
                              void* d_out, int out_size, void* d_ws, size_t ws_size,
                              hipStream_t stream) {
  const float* x     = (const float*)d_in[0];
  const float* w1    = (const float*)d_in[1];
  const float* b1    = (const float*)d_in[2];
  const float* gamma = (const float*)d_in[3];
  const float* beta  = (const float*)d_in[4];
  const float* w2    = (const float*)d_in[5];
  const float* b2    = (const float*)d_in[6];

  float* out  = (float*)d_out;                       // (B,256,56,56)
  float* kout = out + (size_t)NB * C_IN * HW;        // (B,784,56,56) raw == (B,49,56,56,16)

  k1a_conv1<<<dim3(25, 16, 4), 256, 0, stream>>>(x, w1);
  kRT<<<dim3(25, 80), 256, 0, stream>>>(x, b1);
  k3_conv2<<<dim3(13, 49, NB), 256, 0, stream>>>(gamma, beta, w2, b2, kout);
  k4_invol<<<dim3(13, 16, 4), 256, 0, stream>>>(kout, out);
}